// Round 5
// baseline (144.566 us; speedup 1.0000x reference)
//
#include <hip/hip_runtime.h>
#include <math.h>

// Problem constants (from reference setup_inputs)
#define NQ 2048
#define NB 8192
#define DIM 32

#define LOG2E 1.44269504088896340736f

typedef _Float16 half8 __attribute__((ext_vector_type(8)));
typedef float    f32x4 __attribute__((ext_vector_type(4)));

// ---------------- workspace layout (bytes, 64-B aligned) ----------------
#define WS_ACC 0         // 2*NQ f32 (16384 B)
#define WS_CTR 16384     // completion counter (64-B slot)
#define WS_Q2  16448     // NQ f32
#define WS_B2  24640     // NB f32
#define WS_XQH 57408     // NQ*DIM f16   (A operand: xq*w rounded)
#define WS_XBH 188480    // NB*DIM f16   (B operand: -2*(xb*w) rounded-then-scaled)

// Pre: convert rows to f16 with norms computed FROM THE ROUNDED VALUES
// (so mfma d2 = ||a-b||^2 has no representation-mismatch cancellation).
// XBh is stored pre-scaled by -2 (exact: exponent+1 + sign) so the main
// MFMA with C = q2+b2 emits d2 directly.
// Layout: 4 threads/row, 8 elems each -> float4 loads, 16-B half8 stores,
// fully coalesced. 160 blocks (vs 40 in the old scalar version).
__global__ __launch_bounds__(256) void relnw_pre(
    const float* __restrict__ xq, const float* __restrict__ xb,
    const float* __restrict__ w,
    _Float16* __restrict__ XQh, _Float16* __restrict__ XBh,
    float* __restrict__ q2, float* __restrict__ b2,
    float* __restrict__ acc, unsigned* __restrict__ ctr)
{
    const int tid = threadIdx.x;
    const int gi  = blockIdx.x * 256 + tid;
    if (gi < 2 * NQ) acc[gi] = 0.f;      // zero atomic accumulators
    if (gi == 0)     *ctr = 0u;          // zero completion counter

    const int row = blockIdx.x * 64 + (tid >> 2);
    const int p   = tid & 3;             // 8-elem chunk within the row
    if (row >= NQ + NB) return;

    const float* src; _Float16* dst; float* s2; float scale;
    if (row < NQ) { src = xq + (size_t)row * DIM;
                    dst = XQh + (size_t)row * DIM; s2 = q2 + row; scale = 1.f; }
    else          { int j = row - NQ;
                    src = xb + (size_t)j * DIM;
                    dst = XBh + (size_t)j * DIM;   s2 = b2 + j;   scale = -2.f; }

    const float4 xa = ((const float4*)src)[p * 2];
    const float4 xbv = ((const float4*)src)[p * 2 + 1];
    const float4 wa = ((const float4*)w)[p * 2];
    const float4 wb = ((const float4*)w)[p * 2 + 1];
    const float xs[8] = {xa.x, xa.y, xa.z, xa.w, xbv.x, xbv.y, xbv.z, xbv.w};
    const float ws_[8] = {wa.x, wa.y, wa.z, wa.w, wb.x, wb.y, wb.z, wb.w};

    half8 h;
    float s = 0.f;
#pragma unroll
    for (int c = 0; c < 8; ++c) {
        float t = xs[c] * ws_[c];
        _Float16 hh = (_Float16)t;       // the rounding
        float th = (float)hh;
        s = fmaf(th, th, s);             // norm of the ROUNDED vector
        h[c] = (_Float16)(th * scale);   // exact scaling
    }
    *(half8*)(dst + p * 8) = h;          // coalesced 16-B store

    // row-norm: reduce over the 4 chunk-lanes (low 2 lane bits)
    s += __shfl_xor(s, 1, 64);
    s += __shfl_xor(s, 2, 64);
    if (p == 0) *s2 = s;
}

// Main: grid (8, 128) = 1024 blocks (4/CU), 256 threads (4 waves).
// Wave task: one 16-query tile x 256-bg chunk = 16 MFMA tiles.
// v_mfma_f32_16x16x32_f16 with A = xq*w (f16), B = -2*(xb*w) (f16),
// C[g] = q2+b2  ==>  D = d2 directly.
// C/D layout: col = lane&15 (bg), row = (lane>>4)*4 + reg (query).
// Finalize fused: last block to finish computes out = sky/(sk+1e-8)
// via device-coherent atomic reads.
#define BT_PER_WAVE 16
#define BG_PER_WAVE (BT_PER_WAVE * 16)   // 256
#define NBLOCKS (8 * 128)

__global__ __launch_bounds__(256) void relnw_main(
    const _Float16* __restrict__ XQh,  // (NQ, DIM)
    const _Float16* __restrict__ XBh,  // (NB, DIM), pre-scaled by -2
    const float* __restrict__ q2,      // (NQ,)
    const float* __restrict__ b2,      // (NB,)
    const float* __restrict__ yb,      // (NB,)
    const float* __restrict__ r,       // (NQ, NB)
    const float* __restrict__ sigma,   // (1,)
    const float* __restrict__ rscale,  // (1,)
    float* __restrict__ acc,           // [0:NQ]=sum_k, [NQ:2NQ]=sum_k*y
    unsigned* __restrict__ ctr,
    float* __restrict__ out)
{
    const int tid  = threadIdx.x;
    const int lane = tid & 63;
    const int wid  = tid >> 6;
    const int m    = lane & 15;   // A row (query) / B col (bg) / C col (bg)
    const int quad = lane >> 4;   // 0..3

    const int q0     = blockIdx.y * 16;
    const int bstart = (blockIdx.x * 4 + wid) * BG_PER_WAVE;

    const float c1 = -LOG2E / sigma[0];   // coeff on dist (log2 space)
    const float c2 =  LOG2E * rscale[0];  // coeff on r

    // A fragment for this wave's 16 queries (fixed across the b-loop)
    const half8 afrag = *(const half8*)(XQh + (size_t)(q0 + m) * DIM + quad * 8);

    float q2r[4];
#pragma unroll
    for (int g = 0; g < 4; ++g) q2r[g] = q2[q0 + quad * 4 + g];

    const _Float16* xbp = XBh + (size_t)(bstart + m) * DIM + quad * 8;
    const float*    rp  = r + (size_t)(q0 + quad * 4) * NB + bstart + m;

    float sk[4]  = {0.f, 0.f, 0.f, 0.f};
    float sky[4] = {0.f, 0.f, 0.f, 0.f};

#pragma unroll
    for (int it = 0; it < BT_PER_WAVE; ++it) {
        const int bc = bstart + it * 16 + m;            // this lane's bg col
        const half8 bfrag = *(const half8*)(xbp + (size_t)it * 16 * DIM);
        const float yv  = yb[bc];
        const float b2v = b2[bc];
        float rr[4];
#pragma unroll
        for (int g = 0; g < 4; ++g) rr[g] = rp[(size_t)g * NB + it * 16];

        f32x4 cin;
#pragma unroll
        for (int g = 0; g < 4; ++g) cin[g] = q2r[g] + b2v;

        // D = q2 + b2 - 2*dot = d2
        f32x4 d2v = __builtin_amdgcn_mfma_f32_16x16x32_f16(
            afrag, bfrag, cin, 0, 0, 0);

#pragma unroll
        for (int g = 0; g < 4; ++g) {
            float d2 = fmaxf(d2v[g], 0.f);
            float dist = __builtin_amdgcn_sqrtf(d2);
            float e = fmaf(dist, c1, rr[g] * c2);       // log2-space exponent
            float k = __builtin_amdgcn_exp2f(e);
            sk[g] += k;
            sky[g] = fmaf(k, yv, sky[g]);
        }
    }

    // Reduce across the 16 bg-columns (low 4 lane bits), once per wave.
#pragma unroll
    for (int off = 1; off <= 8; off <<= 1) {
#pragma unroll
        for (int g = 0; g < 4; ++g) {
            sk[g]  += __shfl_xor(sk[g],  off, 64);
            sky[g] += __shfl_xor(sky[g], off, 64);
        }
    }
    if (m == 0) {
#pragma unroll
        for (int g = 0; g < 4; ++g) {
            atomicAdd(acc + (q0 + quad * 4 + g),      sk[g]);
            atomicAdd(acc + NQ + (q0 + quad * 4 + g), sky[g]);
        }
    }

    // ---- fused finalize: last block to arrive computes the output ----
    __syncthreads();                      // all waves' atomics issued
    __shared__ int is_last;
    if (tid == 0) {
        __threadfence();                  // make this block's adds visible
        is_last = (atomicAdd(ctr, 1u) == NBLOCKS - 1);
    }
    __syncthreads();
    if (is_last) {
        for (int q = tid; q < NQ; q += 256) {
            // device-coherent reads of the fully-accumulated sums
            float skv  = atomicAdd(acc + q,      0.f);
            float skyv = atomicAdd(acc + NQ + q, 0.f);
            out[q] = skyv / (skv + 1e-8f);
        }
    }
}

extern "C" void kernel_launch(void* const* d_in, const int* in_sizes, int n_in,
                              void* d_out, int out_size, void* d_ws, size_t ws_size,
                              hipStream_t stream) {
    const float* xb     = (const float*)d_in[0]; // (8192,32)
    const float* yb     = (const float*)d_in[1]; // (8192,)
    const float* xq     = (const float*)d_in[2]; // (2048,32)
    const float* r      = (const float*)d_in[3]; // (2048,8192)
    const float* sigma  = (const float*)d_in[4]; // (1,)
    const float* rscale = (const float*)d_in[5]; // (1,)
    const float* w      = (const float*)d_in[6]; // (32,)
    float* out = (float*)d_out;

    char* ws = (char*)d_ws;
    float*    acc = (float*)(ws + WS_ACC);
    unsigned* ctr = (unsigned*)(ws + WS_CTR);
    float*    q2  = (float*)(ws + WS_Q2);
    float*    b2  = (float*)(ws + WS_B2);
    _Float16* XQh = (_Float16*)(ws + WS_XQH);
    _Float16* XBh = (_Float16*)(ws + WS_XBH);

    relnw_pre<<<(NQ + NB) / 64, 256, 0, stream>>>(xq, xb, w, XQh, XBh, q2, b2, acc, ctr);

    dim3 grid(NB / (4 * BG_PER_WAVE), NQ / 16);  // (8, 128) = 1024 blocks
    relnw_main<<<grid, 256, 0, stream>>>(XQh, XBh, q2, b2, yb, r, sigma, rscale,
                                         acc, ctr, out);
}

// Round 6
// 112.774 us; speedup vs baseline: 1.2819x; 1.2819x over previous
//
#include <hip/hip_runtime.h>
#include <math.h>

// Problem constants (from reference setup_inputs)
#define NQ 2048
#define NB 8192
#define DIM 32

#define LOG2E 1.44269504088896340736f

typedef _Float16 half8 __attribute__((ext_vector_type(8)));
typedef float    f32x4 __attribute__((ext_vector_type(4)));

// ---------------- workspace layout (bytes, 64-B aligned) ----------------
#define WS_ACC 0         // 2*NQ f32 (16384 B)
#define WS_Q2  16448     // NQ f32
#define WS_B2  24640     // NB f32
#define WS_XQH 57408     // NQ*DIM f16   (A operand: xq*w rounded)
#define WS_XBH 188480    // NB*DIM f16   (B operand: -2*(xb*w) rounded-then-scaled)

// Pre: convert rows to f16 with norms computed FROM THE ROUNDED VALUES
// (so mfma d2 = ||a-b||^2 has no representation-mismatch cancellation).
// XBh is stored pre-scaled by -2 (exact: exponent+1 + sign) so the main
// MFMA with C = q2+b2 emits d2 directly.
// Layout: 4 threads/row, 8 elems each -> float4 loads, 16-B half8 stores,
// fully coalesced. Also zeroes the atomic accumulators.
__global__ __launch_bounds__(256) void relnw_pre(
    const float* __restrict__ xq, const float* __restrict__ xb,
    const float* __restrict__ w,
    _Float16* __restrict__ XQh, _Float16* __restrict__ XBh,
    float* __restrict__ q2, float* __restrict__ b2,
    float* __restrict__ acc)
{
    const int tid = threadIdx.x;
    const int gi  = blockIdx.x * 256 + tid;
    if (gi < 2 * NQ) acc[gi] = 0.f;      // zero atomic accumulators

    const int row = blockIdx.x * 64 + (tid >> 2);
    const int p   = tid & 3;             // 8-elem chunk within the row
    if (row >= NQ + NB) return;

    const float* src; _Float16* dst; float* s2; float scale;
    if (row < NQ) { src = xq + (size_t)row * DIM;
                    dst = XQh + (size_t)row * DIM; s2 = q2 + row; scale = 1.f; }
    else          { int j = row - NQ;
                    src = xb + (size_t)j * DIM;
                    dst = XBh + (size_t)j * DIM;   s2 = b2 + j;   scale = -2.f; }

    const float4 xa  = ((const float4*)src)[p * 2];
    const float4 xbv = ((const float4*)src)[p * 2 + 1];
    const float4 wa  = ((const float4*)w)[p * 2];
    const float4 wb  = ((const float4*)w)[p * 2 + 1];
    const float xs[8]  = {xa.x, xa.y, xa.z, xa.w, xbv.x, xbv.y, xbv.z, xbv.w};
    const float ws_[8] = {wa.x, wa.y, wa.z, wa.w, wb.x, wb.y, wb.z, wb.w};

    half8 h;
    float s = 0.f;
#pragma unroll
    for (int c = 0; c < 8; ++c) {
        float t = xs[c] * ws_[c];
        _Float16 hh = (_Float16)t;       // the rounding
        float th = (float)hh;
        s = fmaf(th, th, s);             // norm of the ROUNDED vector
        h[c] = (_Float16)(th * scale);   // exact scaling
    }
    *(half8*)(dst + p * 8) = h;          // coalesced 16-B store

    // row-norm: reduce over the 4 chunk-lanes (low 2 lane bits)
    s += __shfl_xor(s, 1, 64);
    s += __shfl_xor(s, 2, 64);
    if (p == 0) *s2 = s;
}

// Main: grid (8, 128) = 1024 blocks (4/CU), 256 threads (4 waves).
// Wave task: one 16-query tile x 256-bg chunk = 16 MFMA tiles.
// v_mfma_f32_16x16x32_f16 with A = xq*w (f16), B = -2*(xb*w) (f16),
// C[g] = q2+b2  ==>  D = d2 directly.
// C/D layout: col = lane&15 (bg), row = (lane>>4)*4 + reg (query).
// NOTE (R5 lesson): no __threadfence / fused finalize here — a per-block
// agent-scope fence emits buffer_wbl2/inv (full L2 writeback+invalidate),
// and 1024 of them thrashed the L2 for all in-flight blocks (VALUBusy
// 44%->8%, 2.5x slowdown, FETCH unchanged because L3 absorbed refills).
#define BT_PER_WAVE 16
#define BG_PER_WAVE (BT_PER_WAVE * 16)   // 256

__global__ __launch_bounds__(256) void relnw_main(
    const _Float16* __restrict__ XQh,  // (NQ, DIM)
    const _Float16* __restrict__ XBh,  // (NB, DIM), pre-scaled by -2
    const float* __restrict__ q2,      // (NQ,)
    const float* __restrict__ b2,      // (NB,)
    const float* __restrict__ yb,      // (NB,)
    const float* __restrict__ r,       // (NQ, NB)
    const float* __restrict__ sigma,   // (1,)
    const float* __restrict__ rscale,  // (1,)
    float* __restrict__ acc)           // [0:NQ]=sum_k, [NQ:2NQ]=sum_k*y
{
    const int tid  = threadIdx.x;
    const int lane = tid & 63;
    const int wid  = tid >> 6;
    const int m    = lane & 15;   // A row (query) / B col (bg) / C col (bg)
    const int quad = lane >> 4;   // 0..3

    const int q0     = blockIdx.y * 16;
    const int bstart = (blockIdx.x * 4 + wid) * BG_PER_WAVE;

    const float c1 = -LOG2E / sigma[0];   // coeff on dist (log2 space)
    const float c2 =  LOG2E * rscale[0];  // coeff on r

    // A fragment for this wave's 16 queries (fixed across the b-loop)
    const half8 afrag = *(const half8*)(XQh + (size_t)(q0 + m) * DIM + quad * 8);

    float q2r[4];
#pragma unroll
    for (int g = 0; g < 4; ++g) q2r[g] = q2[q0 + quad * 4 + g];

    const _Float16* xbp = XBh + (size_t)(bstart + m) * DIM + quad * 8;
    const float*    rp  = r + (size_t)(q0 + quad * 4) * NB + bstart + m;

    float sk[4]  = {0.f, 0.f, 0.f, 0.f};
    float sky[4] = {0.f, 0.f, 0.f, 0.f};

#pragma unroll
    for (int it = 0; it < BT_PER_WAVE; ++it) {
        const int bc = bstart + it * 16 + m;            // this lane's bg col
        const half8 bfrag = *(const half8*)(xbp + (size_t)it * 16 * DIM);
        const float yv  = yb[bc];
        const float b2v = b2[bc];
        float rr[4];
#pragma unroll
        for (int g = 0; g < 4; ++g) rr[g] = rp[(size_t)g * NB + it * 16];

        f32x4 cin;
#pragma unroll
        for (int g = 0; g < 4; ++g) cin[g] = q2r[g] + b2v;

        // D = q2 + b2 - 2*dot = d2
        f32x4 d2v = __builtin_amdgcn_mfma_f32_16x16x32_f16(
            afrag, bfrag, cin, 0, 0, 0);

#pragma unroll
        for (int g = 0; g < 4; ++g) {
            float d2 = fmaxf(d2v[g], 0.f);
            float dist = __builtin_amdgcn_sqrtf(d2);
            float e = fmaf(dist, c1, rr[g] * c2);       // log2-space exponent
            float k = __builtin_amdgcn_exp2f(e);
            sk[g] += k;
            sky[g] = fmaf(k, yv, sky[g]);
        }
    }

    // Reduce across the 16 bg-columns (low 4 lane bits), once per wave.
#pragma unroll
    for (int off = 1; off <= 8; off <<= 1) {
#pragma unroll
        for (int g = 0; g < 4; ++g) {
            sk[g]  += __shfl_xor(sk[g],  off, 64);
            sky[g] += __shfl_xor(sky[g], off, 64);
        }
    }
    if (m == 0) {
#pragma unroll
        for (int g = 0; g < 4; ++g) {
            atomicAdd(acc + (q0 + quad * 4 + g),      sk[g]);
            atomicAdd(acc + NQ + (q0 + quad * 4 + g), sky[g]);
        }
    }
}

__global__ __launch_bounds__(256) void relnw_finalize(
    const float* __restrict__ acc, float* __restrict__ out)
{
    int q = blockIdx.x * 256 + threadIdx.x;
    if (q < NQ)
        out[q] = acc[NQ + q] / (acc[q] + 1e-8f);
}

extern "C" void kernel_launch(void* const* d_in, const int* in_sizes, int n_in,
                              void* d_out, int out_size, void* d_ws, size_t ws_size,
                              hipStream_t stream) {
    const float* xb     = (const float*)d_in[0]; // (8192,32)
    const float* yb     = (const float*)d_in[1]; // (8192,)
    const float* xq     = (const float*)d_in[2]; // (2048,32)
    const float* r      = (const float*)d_in[3]; // (2048,8192)
    const float* sigma  = (const float*)d_in[4]; // (1,)
    const float* rscale = (const float*)d_in[5]; // (1,)
    const float* w      = (const float*)d_in[6]; // (32,)
    float* out = (float*)d_out;

    char* ws = (char*)d_ws;
    float*    acc = (float*)(ws + WS_ACC);
    float*    q2  = (float*)(ws + WS_Q2);
    float*    b2  = (float*)(ws + WS_B2);
    _Float16* XQh = (_Float16*)(ws + WS_XQH);
    _Float16* XBh = (_Float16*)(ws + WS_XBH);

    relnw_pre<<<(NQ + NB) / 64, 256, 0, stream>>>(xq, xb, w, XQh, XBh, q2, b2, acc);

    dim3 grid(NB / (4 * BG_PER_WAVE), NQ / 16);  // (8, 128) = 1024 blocks
    relnw_main<<<grid, 256, 0, stream>>>(XQh, XBh, q2, b2, yb, r, sigma, rscale, acc);

    relnw_finalize<<<(NQ + 255) / 256, 256, 0, stream>>>(acc, out);
}

// Round 7
// 112.713 us; speedup vs baseline: 1.2826x; 1.0005x over previous
//
#include <hip/hip_runtime.h>
#include <math.h>

// Problem constants (from reference setup_inputs)
#define NQ 2048
#define NB 8192
#define DIM 32

#define LOG2E 1.44269504088896340736f

typedef _Float16 half8 __attribute__((ext_vector_type(8)));
typedef float    f32x4 __attribute__((ext_vector_type(4)));

// ---------------- workspace layout (bytes, 64-B aligned) ----------------
#define WS_ACC 0         // 2*NQ f32 (16384 B)
#define WS_Q2  16448     // NQ f32
#define WS_B2  24640     // NB f32
#define WS_XQH 57408     // NQ*DIM f16   (A operand: xq*w rounded)
#define WS_XBH 188480    // NB*DIM f16   (B operand: -2*(xb*w) rounded-then-scaled)

// Pre: convert rows to f16 with norms computed FROM THE ROUNDED VALUES
// (so mfma d2 = ||a-b||^2 has no representation-mismatch cancellation).
// XBh is stored pre-scaled by -2 (exact: exponent+1 + sign) so the main
// MFMA with C = q2+b2 emits d2 directly.
__global__ __launch_bounds__(256) void relnw_pre(
    const float* __restrict__ xq, const float* __restrict__ xb,
    const float* __restrict__ w,
    _Float16* __restrict__ XQh, _Float16* __restrict__ XBh,
    float* __restrict__ q2, float* __restrict__ b2,
    float* __restrict__ acc)
{
    const int tid = threadIdx.x;
    const int gi  = blockIdx.x * 256 + tid;
    if (gi < 2 * NQ) acc[gi] = 0.f;      // zero atomic accumulators

    const int row = blockIdx.x * 64 + (tid >> 2);
    const int p   = tid & 3;             // 8-elem chunk within the row
    if (row >= NQ + NB) return;

    const float* src; _Float16* dst; float* s2; float scale;
    if (row < NQ) { src = xq + (size_t)row * DIM;
                    dst = XQh + (size_t)row * DIM; s2 = q2 + row; scale = 1.f; }
    else          { int j = row - NQ;
                    src = xb + (size_t)j * DIM;
                    dst = XBh + (size_t)j * DIM;   s2 = b2 + j;   scale = -2.f; }

    const float4 xa  = ((const float4*)src)[p * 2];
    const float4 xbv = ((const float4*)src)[p * 2 + 1];
    const float4 wa  = ((const float4*)w)[p * 2];
    const float4 wb  = ((const float4*)w)[p * 2 + 1];
    const float xs[8]  = {xa.x, xa.y, xa.z, xa.w, xbv.x, xbv.y, xbv.z, xbv.w};
    const float ws_[8] = {wa.x, wa.y, wa.z, wa.w, wb.x, wb.y, wb.z, wb.w};

    half8 h;
    float s = 0.f;
#pragma unroll
    for (int c = 0; c < 8; ++c) {
        float t = xs[c] * ws_[c];
        _Float16 hh = (_Float16)t;       // the rounding
        float th = (float)hh;
        s = fmaf(th, th, s);             // norm of the ROUNDED vector
        h[c] = (_Float16)(th * scale);   // exact scaling
    }
    *(half8*)(dst + p * 8) = h;          // coalesced 16-B store

    // row-norm: reduce over the 4 chunk-lanes (low 2 lane bits)
    s += __shfl_xor(s, 1, 64);
    s += __shfl_xor(s, 2, 64);
    if (p == 0) *s2 = s;
}

// Main: grid (8, 128) = 1024 blocks (4/CU), 256 threads (4 waves).
// Wave task: one 16-query tile x 256-bg chunk = 16 MFMA tiles.
// v_mfma_f32_16x16x32_f16 with A = xq*w (f16), B = -2*(xb*w) (f16),
// C[g] = q2+b2  ==>  D = d2 directly.
// C/D layout: col = lane&15 (bg), row = (lane>>4)*4 + reg (query).
//
// R6 analysis: main ran at ~1.9 TB/s effective on the r stream — memory-
// LATENCY bound (each iteration issued ~7 loads then waited; compute/iter
// ~100cy << load latency ~600cy). Fix: double-buffered batch prefetch of r,
// 4 iterations (16 loads) in flight per wave. All r loads are immediate-
// offset off 4 row-base pointers (offsets <= 960 B < 4 KiB imm range).
//
// R5 lesson (keep): no __threadfence / fused finalize — a per-block agent-
// scope fence emits buffer_wbl2/inv and thrashes L2 for in-flight blocks.
#define BT_PER_WAVE 16
#define BG_PER_WAVE (BT_PER_WAVE * 16)   // 256
#define RB 4                             // r-prefetch batch (iterations)

__global__ __launch_bounds__(256) void relnw_main(
    const _Float16* __restrict__ XQh,  // (NQ, DIM)
    const _Float16* __restrict__ XBh,  // (NB, DIM), pre-scaled by -2
    const float* __restrict__ q2,      // (NQ,)
    const float* __restrict__ b2,      // (NB,)
    const float* __restrict__ yb,      // (NB,)
    const float* __restrict__ r,       // (NQ, NB)
    const float* __restrict__ sigma,   // (1,)
    const float* __restrict__ rscale,  // (1,)
    float* __restrict__ acc)           // [0:NQ]=sum_k, [NQ:2NQ]=sum_k*y
{
    const int tid  = threadIdx.x;
    const int lane = tid & 63;
    const int wid  = tid >> 6;
    const int m    = lane & 15;   // A row (query) / B col (bg) / C col (bg)
    const int quad = lane >> 4;   // 0..3

    const int q0     = blockIdx.y * 16;
    const int bstart = (blockIdx.x * 4 + wid) * BG_PER_WAVE;

    const float c1 = -LOG2E / sigma[0];   // coeff on dist (log2 space)
    const float c2 =  LOG2E * rscale[0];  // coeff on r

    // A fragment for this wave's 16 queries (fixed across the b-loop)
    const half8 afrag = *(const half8*)(XQh + (size_t)(q0 + m) * DIM + quad * 8);

    float q2r[4];
#pragma unroll
    for (int g = 0; g < 4; ++g) q2r[g] = q2[q0 + quad * 4 + g];

    const _Float16* xbp = XBh + (size_t)(bstart + m) * DIM + quad * 8;

    // 4 r row-base pointers; every r load below is base + compile-time offset
    const float* rbase[4];
#pragma unroll
    for (int g = 0; g < 4; ++g)
        rbase[g] = r + (size_t)(q0 + quad * 4 + g) * NB + bstart + m;

    float sk[4]  = {0.f, 0.f, 0.f, 0.f};
    float sky[4] = {0.f, 0.f, 0.f, 0.f};

    // double-buffered r prefetch, RB iterations per batch
    float rr[2][RB][4];
#pragma unroll
    for (int i = 0; i < RB; ++i)
#pragma unroll
        for (int g = 0; g < 4; ++g)
            rr[0][i][g] = rbase[g][i * 16];

#pragma unroll
    for (int bt = 0; bt < BT_PER_WAVE / RB; ++bt) {
        const int cur = bt & 1;
        if (bt + 1 < BT_PER_WAVE / RB) {
#pragma unroll
            for (int i = 0; i < RB; ++i)
#pragma unroll
                for (int g = 0; g < 4; ++g)
                    rr[cur ^ 1][i][g] = rbase[g][((bt + 1) * RB + i) * 16];
        }
#pragma unroll
        for (int i = 0; i < RB; ++i) {
            const int it = bt * RB + i;
            const int bc = bstart + it * 16 + m;        // this lane's bg col
            const half8 bfrag = *(const half8*)(xbp + (size_t)it * 16 * DIM);
            const float yv  = yb[bc];
            const float b2v = b2[bc];

            f32x4 cin;
#pragma unroll
            for (int g = 0; g < 4; ++g) cin[g] = q2r[g] + b2v;

            // D = q2 + b2 - 2*dot = d2
            f32x4 d2v = __builtin_amdgcn_mfma_f32_16x16x32_f16(
                afrag, bfrag, cin, 0, 0, 0);

#pragma unroll
            for (int g = 0; g < 4; ++g) {
                float d2 = fmaxf(d2v[g], 0.f);
                float dist = __builtin_amdgcn_sqrtf(d2);
                float e = fmaf(dist, c1, rr[cur][i][g] * c2); // log2 space
                float k = __builtin_amdgcn_exp2f(e);
                sk[g] += k;
                sky[g] = fmaf(k, yv, sky[g]);
            }
        }
    }

    // Reduce across the 16 bg-columns (low 4 lane bits), once per wave.
#pragma unroll
    for (int off = 1; off <= 8; off <<= 1) {
#pragma unroll
        for (int g = 0; g < 4; ++g) {
            sk[g]  += __shfl_xor(sk[g],  off, 64);
            sky[g] += __shfl_xor(sky[g], off, 64);
        }
    }
    if (m == 0) {
#pragma unroll
        for (int g = 0; g < 4; ++g) {
            atomicAdd(acc + (q0 + quad * 4 + g),      sk[g]);
            atomicAdd(acc + NQ + (q0 + quad * 4 + g), sky[g]);
        }
    }
}

__global__ __launch_bounds__(256) void relnw_finalize(
    const float* __restrict__ acc, float* __restrict__ out)
{
    int q = blockIdx.x * 256 + threadIdx.x;
    if (q < NQ)
        out[q] = acc[NQ + q] / (acc[q] + 1e-8f);
}

extern "C" void kernel_launch(void* const* d_in, const int* in_sizes, int n_in,
                              void* d_out, int out_size, void* d_ws, size_t ws_size,
                              hipStream_t stream) {
    const float* xb     = (const float*)d_in[0]; // (8192,32)
    const float* yb     = (const float*)d_in[1]; // (8192,)
    const float* xq     = (const float*)d_in[2]; // (2048,32)
    const float* r      = (const float*)d_in[3]; // (2048,8192)
    const float* sigma  = (const float*)d_in[4]; // (1,)
    const float* rscale = (const float*)d_in[5]; // (1,)
    const float* w      = (const float*)d_in[6]; // (32,)
    float* out = (float*)d_out;

    char* ws = (char*)d_ws;
    float*    acc = (float*)(ws + WS_ACC);
    float*    q2  = (float*)(ws + WS_Q2);
    float*    b2  = (float*)(ws + WS_B2);
    _Float16* XQh = (_Float16*)(ws + WS_XQH);
    _Float16* XBh = (_Float16*)(ws + WS_XBH);

    relnw_pre<<<(NQ + NB) / 64, 256, 0, stream>>>(xq, xb, w, XQh, XBh, q2, b2, acc);

    dim3 grid(NB / (4 * BG_PER_WAVE), NQ / 16);  // (8, 128) = 1024 blocks
    relnw_main<<<grid, 256, 0, stream>>>(XQh, XBh, q2, b2, yb, r, sigma, rscale, acc);

    relnw_finalize<<<(NQ + 255) / 256, 256, 0, stream>>>(acc, out);
}